// Round 2
// baseline (168.563 us; speedup 1.0000x reference)
//
#include <hip/hip_runtime.h>
#include <cfloat>
#include <cmath>

#define N_NODES 20000
#define MAXD 32
#define F 128

// ---------------- stage 1: trimmed-mean aggregation ----------------

// Batcher odd-even mergesort network, ascending, fully unrolled.
// CE counts: SZ=4:5, 8:19, 16:63, 32:191 (vs bitonic 6/24/80/240).
template <int SZ>
__device__ __forceinline__ void oe_sort(float (&a)[SZ]) {
#pragma unroll
  for (int p = 1; p < SZ; p <<= 1) {
#pragma unroll
    for (int q = p; q >= 1; q >>= 1) {
#pragma unroll
      for (int j = q % p; j <= SZ - 1 - q; j += 2 * q) {
#pragma unroll
        for (int i = 0; i < q; ++i) {
          int x = i + j, y = i + j + q;
          if (y < SZ && (x / (2 * p)) == (y / (2 * p))) {
            float mn = fminf(a[x], a[y]);
            float mx = fmaxf(a[x], a[y]);
            a[x] = mn;
            a[y] = mx;
          }
        }
      }
    }
  }
}

// extract element at (block-uniform) position p from a statically-indexed register array
template <int SZ>
__device__ __forceinline__ float extract_pos(const float (&k)[SZ], int p) {
  float sel[SZ];
#pragma unroll
  for (int i = 0; i < SZ; ++i) sel[i] = k[i];
#pragma unroll
  for (int w = SZ >> 1; w >= 1; w >>= 1) {
    bool take = (p & w) != 0;
#pragma unroll
    for (int i = 0; i < w; ++i) sel[i] = take ? sel[i + w] : sel[i];
  }
  return sel[0];
}

// Exact trimmed sum: payloads (key*norm_src) whose STABLE rank (key asc, ties
// by slot — matches jnp.argsort) lies in [b, n-b).
// Fast path: when sorted[b-1] < sorted[b] and sorted[n-b-1] < sorted[n-b],
// rank-membership == value-membership in [lo, hi] (exact, incl. lo==hi runs).
// Slow path (rare: boundary ties, ~2.5% of nodes): round-1 verified scan.
template <int SZ>
__device__ __forceinline__ float trimmed_sum(const float* __restrict__ h,
                                             const float* __restrict__ norm,
                                             const int* __restrict__ nbr_row,
                                             int n, int f, int b) {
  float ko[SZ];
  float nrm[SZ];  // block-uniform -> SGPRs
#pragma unroll
  for (int d = 0; d < SZ; ++d) {
    if (d < n) {  // uniform branch (n is block-uniform)
      int src = nbr_row[d];       // scalar load
      nrm[d] = norm[src];         // scalar load
      ko[d] = h[src * F + f];     // vector load, coalesced
    } else {
      nrm[d] = 0.f;
      ko[d] = FLT_MAX;            // pads sort past all valid keys
    }
  }

  float k[SZ];
#pragma unroll
  for (int d = 0; d < SZ; ++d) k[d] = ko[d];
  oe_sort<SZ>(k);

  const float lo  = extract_pos<SZ>(k, b);          // rank b (kept)
  const float hi  = extract_pos<SZ>(k, n - b - 1);  // rank n-b-1 (kept)
  const float lom = extract_pos<SZ>(k, b - 1);      // rank b-1 (trimmed)
  const float him = extract_pos<SZ>(k, n - b);      // rank n-b (trimmed)

  float sum = 0.f;
  if ((lom < lo) & (hi < him)) {
    // no equal-key run straddles either boundary -> pure value test.
    // pads (FLT_MAX) fail ko<=hi since hi < him <= FLT_MAX.
#pragma unroll
    for (int d = 0; d < SZ; ++d) {
      bool keep = (ko[d] >= lo) & (ko[d] <= hi);
      sum = fmaf(keep ? ko[d] : 0.f, nrm[d], sum);
    }
  } else {
    int c_lt_lo = 0, c_lt_hi = 0;
#pragma unroll
    for (int d = 0; d < SZ; ++d) {
      c_lt_lo += (ko[d] < lo) ? 1 : 0;
      c_lt_hi += (ko[d] < hi) ? 1 : 0;
    }
    int run_lo = 0, run_hi = 0;
    const int nb = n - b;
#pragma unroll
    for (int d = 0; d < SZ; ++d) {
      const float kd = ko[d];
      const float m = kd * nrm[d];  // pads: FLT_MAX*0 = 0
      const bool eql = (kd == lo);
      const bool eqh = (kd == hi);
      const bool lh = (lo < hi);
      const bool btw = (kd > lo) & (kd < hi);
      const int r_lo = c_lt_lo + run_lo;  // stable rank if kd==lo
      const int r_hi = c_lt_hi + run_hi;  // stable rank if kd==hi
      const bool inc = btw
                     | (eql & (r_lo >= b) & (lh | (r_lo < nb)))
                     | (lh & eqh & (r_hi < nb));
      sum += inc ? m : 0.f;
      run_lo += eql ? 1 : 0;
      run_hi += eqh ? 1 : 0;
    }
  }
  return sum;
}

__global__ __launch_bounds__(128, 4) void gcn_stage1(const float* __restrict__ h,
                                                     const float* __restrict__ norm,
                                                     const int* __restrict__ nbr,
                                                     const int* __restrict__ deg,
                                                     float* __restrict__ accum) {
  const int i = blockIdx.x;
  const int f = threadIdx.x;
  const int n = deg[i];            // block-uniform
  const float ni = norm[i];
  const float hif = h[i * F + f];
  const int idx = i * F + f;

  if (n <= 3) {  // N_NEIGH_THRESHOLD branch
    accum[idx] = (float)n * hif * ni * ni;
    return;
  }

  int b = n / 2 - (1 - (n & 1));
  int bcap = (int)floorf((float)n * 0.45f);
  b = b < bcap ? b : bcap;
  b = b > 1 ? b : 1;

  const int* nbr_row = nbr + i * MAXD;
  float ts;
  if (n <= 4)       ts = trimmed_sum<4>(h, norm, nbr_row, n, f, b);
  else if (n <= 8)  ts = trimmed_sum<8>(h, norm, nbr_row, n, f, b);
  else if (n <= 16) ts = trimmed_sum<16>(h, norm, nbr_row, n, f, b);
  else              ts = trimmed_sum<32>(h, norm, nbr_row, n, f, b);

  accum[idx] = (ts + hif * ni * (float)(2 * b)) * ni;
}

// ---------------- stage 2: out = relu(accum @ W + bias) ----------------
// 256 threads, 32 rows x 128 cols per block; per-thread 16 rows x 1 col.
// W staged per 32-k chunk as k-quad float4s (conflict-free b128 LDS traffic);
// A operands are wave-uniform global float4 broadcasts (vmem pipe, L1/L2-hot).
__global__ __launch_bounds__(256) void gcn_gemm(const float* __restrict__ A,
                                                const float* __restrict__ W,
                                                const float* __restrict__ bias,
                                                float* __restrict__ out) {
  __shared__ float4 Wt4[8][128];  // 16 KB: [k-quad q][col c] = W[kc+4q+j][c] in comp j
  const int t = threadIdx.x;
  const int c = t & 127;
  const int rg = t >> 7;                       // 0/1: row half (wave-uniform)
  const int row0 = blockIdx.x * 32 + rg * 16;

  float acc[16];
#pragma unroll
  for (int r = 0; r < 16; ++r) acc[r] = 0.f;

#pragma unroll
  for (int kc = 0; kc < 128; kc += 32) {
    __syncthreads();  // protect Wt4 from previous chunk's readers
#pragma unroll
    for (int qq = 0; qq < 4; ++qq) {
      int q = rg * 4 + qq;
      float4 v;
      v.x = W[(kc + 4 * q + 0) * F + c];   // coalesced 256B/wave per row
      v.y = W[(kc + 4 * q + 1) * F + c];
      v.z = W[(kc + 4 * q + 2) * F + c];
      v.w = W[(kc + 4 * q + 3) * F + c];
      Wt4[q][c] = v;                       // b128 write, all words distinct -> conflict-free
    }
    __syncthreads();
#pragma unroll
    for (int q = 0; q < 8; ++q) {
      float4 w4 = Wt4[q][c];               // b128, conflict-free
      const float* Ab = A + row0 * F + kc + 4 * q;
#pragma unroll
      for (int r = 0; r < 16; ++r) {
        float4 a4 = *(const float4*)(Ab + r * F);  // wave-uniform broadcast, 16B aligned
        acc[r] = fmaf(a4.x, w4.x, acc[r]);
        acc[r] = fmaf(a4.y, w4.y, acc[r]);
        acc[r] = fmaf(a4.z, w4.z, acc[r]);
        acc[r] = fmaf(a4.w, w4.w, acc[r]);
      }
    }
  }

  const float bv = bias[c];
#pragma unroll
  for (int r = 0; r < 16; ++r) {
    out[(row0 + r) * F + c] = fmaxf(acc[r] + bv, 0.f);  // coalesced 256B/wave
  }
}

extern "C" void kernel_launch(void* const* d_in, const int* in_sizes, int n_in,
                              void* d_out, int out_size, void* d_ws, size_t ws_size,
                              hipStream_t stream) {
  const float* h = (const float*)d_in[0];
  const float* norm = (const float*)d_in[1];
  const float* weight = (const float*)d_in[2];
  const float* bias = (const float*)d_in[3];
  const int* nbr = (const int*)d_in[4];
  const int* deg = (const int*)d_in[5];
  float* out = (float*)d_out;
  float* accum = (float*)d_ws;  // 20000*128*4 = 10.24 MB scratch

  gcn_stage1<<<N_NODES, 128, 0, stream>>>(h, norm, nbr, deg, accum);
  gcn_gemm<<<N_NODES / 32, 256, 0, stream>>>(accum, weight, bias, out);
}